// Round 20
// baseline (1184.054 us; speedup 1.0000x reference)
//
#include <hip/hip_runtime.h>
#include <hip/hip_cooperative_groups.h>

namespace cg = cooperative_groups;

// LSTM B=64 T=256 I=512 H=1024, fp32 in/out, fp16 MFMA compute (fp32 accum).
// Round 20: R19 (validated 1096us) + two deltas:
//  1) persist fast: two-accumulator h-MFMA chains, dataflow-carried guards on
//     BOTH accs (R8's interleave is safe now that guard drift is fixed).
//  2) xg_gemm v5: 2 unit-groups per block (BN=128, 128KB LDS W_x stage);
//     each A-load feeds 8 B-tiles. A-traffic 1.07GB -> 536MB.

using f32x4 = __attribute__((ext_vector_type(4))) float;
using u32x4 = __attribute__((ext_vector_type(4))) unsigned int;

#define NB 64
#define NT 256
#define NI 512
#define NH 1024

// ---- workspace layout (bytes) ----
#define OFF_WHH  0u
#define SZ_WHH   (4u*1024u*1024u*2u)        // fp16 [4 g][1024 u][1024 k]
#define OFF_WXH  (OFF_WHH + SZ_WHH)
#define SZ_WXH   (4u*1024u*512u*2u)         // fp16 [4 g][1024 u][512 k]
#define OFF_XH   (OFF_WXH + SZ_WXH)
#define SZ_XH    (256u*64u*512u*2u)         // fp16 [T][B][I]
#define OFF_BIAS (OFF_XH + SZ_XH)
#define SZ_BIAS  (4096u*4u)
#define OFF_HG   (OFF_BIAS + SZ_BIAS)
#define SZ_HG    (2u*4u*16u*1024u*2u)       // fp16 [2 buf][4 bt][16 b][1024 u]
#define OFF_FLG  (OFF_HG + SZ_HG)
#define SZ_FLG   (256u*4u*64u*4u)           // u32 [T][4 bt][64 ug] per-producer
#define OFF_XG   (OFF_FLG + SZ_FLG)
#define SZ_XG    (256ull*64ull*4ull*1024ull*2ull)  // fp16 [T][B][4 g][1024 u]

// ---- LDS layouts (bytes) ----
#define L_H    0        // 16 rows x 2048 B (fp16 [16 b][1024 k], XOR-swizzled)
#define L_WX   32768    // (slow path) 64 rows x 1024 B swizzled W_x
#define L_ACC_S  98304  // slow path: fp32 [4 g][16 b][17]
#define L_HOUT_S 102656
#define LDS_SLOW 103168
#define L_ACC_F  32768  // fast path: fp32 [4 g][272] = 4352 B
#define L_HOUT_F 37120  // fp16 [16 b][16 u] = 512 B
#define LDS_FAST 37632  // R15-validated
#define XG_LDS   131072 // v5: 128 rows x 1024 B swizzled W_x (2 ug)

// dataflow-carried hazard guards (validated R15)
#define GUARD_PRE(acc)  asm volatile("s_nop 1\ns_nop 1" : "+v"(acc))
#define GUARD_POST(acc) asm volatile("s_nop 7\ns_nop 7\ns_nop 7" : "+v"(acc))

__device__ __forceinline__ unsigned short f2h(float f) {
  _Float16 h = (_Float16)f;
  return __builtin_bit_cast(unsigned short, h);
}
__device__ __forceinline__ float h2f(unsigned short u) {
  _Float16 h = __builtin_bit_cast(_Float16, u);
  return (float)h;
}
__device__ __forceinline__ float sigmoid_f(float x) {
  return 1.0f / (1.0f + __expf(-x));
}
__device__ __forceinline__ float tanh_f(float x) {
  float xc = fminf(fmaxf(x, -15.0f), 15.0f);
  float e = __expf(2.0f * xc);
  return 1.0f - 2.0f / (e + 1.0f);
}

// ---------------- prep kernels ----------------

__global__ __launch_bounds__(256) void pack_w_kernel(
    const float* __restrict__ Wh, const float* __restrict__ Wx,
    unsigned short* __restrict__ WhP, unsigned short* __restrict__ WxP) {
  int base = (blockIdx.x * 256 + threadIdx.x) * 4;
  const int nWh = 4 * 1024 * 1024;
  const int nWx = 4 * 1024 * 512;
  if (base < nWh) {
    const float* s = Wh + base;
    unsigned int o0 = (unsigned int)f2h(s[0]) | ((unsigned int)f2h(s[1]) << 16);
    unsigned int o1 = (unsigned int)f2h(s[2]) | ((unsigned int)f2h(s[3]) << 16);
    ((unsigned int*)(WhP + base))[0] = o0;
    ((unsigned int*)(WhP + base))[1] = o1;
  } else {
    int b2 = base - nWh;
    if (b2 < nWx) {
      const float* s = Wx + b2;
      unsigned int o0 = (unsigned int)f2h(s[0]) | ((unsigned int)f2h(s[1]) << 16);
      unsigned int o1 = (unsigned int)f2h(s[2]) | ((unsigned int)f2h(s[3]) << 16);
      ((unsigned int*)(WxP + b2))[0] = o0;
      ((unsigned int*)(WxP + b2))[1] = o1;
    }
  }
}

// transpose x[B][T][I] fp32 -> xh[T][B][I] fp16
__global__ __launch_bounds__(256) void pack_x_kernel(
    const float* __restrict__ x, unsigned short* __restrict__ xh) {
  int gid = blockIdx.x * 256 + threadIdx.x;     // over B*T*(I/8) = 1,048,576
  int i8 = gid & 63;
  int t  = (gid >> 6) & 255;
  int b  = gid >> 14;
  const float* s = x + (((size_t)b * NT + t) * NI + i8 * 8);
  unsigned int w[4];
#pragma unroll
  for (int j = 0; j < 4; ++j)
    w[j] = (unsigned int)f2h(s[2*j]) | ((unsigned int)f2h(s[2*j+1]) << 16);
  u32x4 v = {w[0], w[1], w[2], w[3]};
  *(u32x4*)(xh + (((size_t)t * NB + b) * NI + i8 * 8)) = v;
}

__global__ __launch_bounds__(256) void prep_small_kernel(
    const float* __restrict__ b_x, const float* __restrict__ b_h,
    const float* __restrict__ w_B, const float* __restrict__ b_B,
    float* __restrict__ bias) {
  int gid = blockIdx.x * 256 + threadIdx.x;
  if (gid < 4096) bias[gid] = b_x[gid] + b_h[gid] + w_B[gid] + b_B[gid];
}

// ---------------- xg precompute GEMM v5 (BN=128) ----------
// xg[t][b][g][u] = sum_k xh[t][b][k] * Wx[g*1024+u][k]   (fp16 out)
// Grid 2048 = (mchunk 64) x (ug2 32). Block stages W_x for 2 unit-groups
// (128 rows x 1KB = 128KB LDS, rr = g*32 + uu). Wave w owns M-tiles
// mc*16 + w*4 + i; loads A once, computes 4 gates x 2 unit-subtiles.

__global__ __launch_bounds__(256) void xg_gemm(
    const unsigned short* __restrict__ Wxh,
    const unsigned short* __restrict__ xh,
    unsigned short* __restrict__ xg) {
  extern __shared__ char smem[];
  const int ug2 = blockIdx.x & 31;      // 32 units each
  const int mc  = blockIdx.x >> 5;      // 0..63
  const int tid  = threadIdx.x;
  const int w    = tid >> 6;
  const int l15  = tid & 15;
  const int kg   = (tid & 63) >> 4;

  // ---- stage W_x rows (128 rows: rr = g*32 + uu), swizzled ----
  {
    int rr = tid >> 1, seg = tid & 1;          // rr 0..127, 2 segs x 32 chunks
    int gg = rr >> 5, uu = rr & 31;
    const unsigned short* wsrc = Wxh + ((size_t)(gg * 1024 + ug2 * 32 + uu)) * 512;
    char* row = smem + rr * 1024;
    int sw = (rr & 7) << 4;
#pragma unroll
    for (int j = 0; j < 32; ++j) {
      int chunk = seg * 32 + j;                // 64 x 16B chunks per row
      u32x4 v = *(const u32x4*)(wsrc + chunk * 8);
      *(u32x4*)(row + ((chunk * 16) ^ sw)) = v;
    }
  }
  __syncthreads();

  const int swl = (l15 & 7) << 4;

#pragma unroll 1
  for (int i = 0; i < 4; ++i) {
    const int mt = mc * 16 + w * 4 + i;
    const int t  = mt >> 2;
    const int b0 = (mt & 3) << 4;

    // ---- A fragments once into registers (shared across 8 B-tiles) ----
    u32x4 xa[16];
    const unsigned short* xp = xh + ((size_t)t * NB + b0 + l15) * NI + kg * 8;
#pragma unroll
    for (int kc = 0; kc < 16; ++kc) xa[kc] = *(const u32x4*)(xp + kc * 32);

#pragma unroll 1
    for (int gg = 0; gg < 4; ++gg) {
#pragma unroll 1
      for (int us = 0; us < 2; ++us) {
        f32x4 acc = {0.0f, 0.0f, 0.0f, 0.0f};
        GUARD_PRE(acc);
        const char* wxrow = smem + (gg * 32 + us * 16 + l15) * 1024;
#pragma unroll
        for (int kc = 0; kc < 16; ++kc) {
          u32x4 b = *(const u32x4*)(wxrow + ((kc * 64 + kg * 16) ^ swl));
          asm("v_mfma_f32_16x16x32_f16 %0, %1, %2, %0" : "+v"(acc) : "v"(xa[kc]), "v"(b));
        }
        GUARD_POST(acc);

#pragma unroll
        for (int r = 0; r < 4; ++r) {
          size_t addr = (((size_t)t * NB + b0 + kg * 4 + r) * 4 + gg) * 1024
                      + ug2 * 32 + us * 16 + l15;
          xg[addr] = f2h(acc[r]);
        }
      }
    }
  }
}

// ---------------- persistent LSTM kernel: SLOW path (R15-validated) --------

__global__ __launch_bounds__(256, 1) void lstm_persist_slow(
    const unsigned short* __restrict__ Whh,
    const unsigned short* __restrict__ Wxh,
    const unsigned short* __restrict__ xh,
    const float* __restrict__ bias,
    unsigned short* __restrict__ hglob,
    unsigned int* __restrict__ flags,
    float* __restrict__ out) {
  extern __shared__ char smem[];
  const int bid  = blockIdx.x;
  const int bt   = bid & 3;
  const int ug   = bid >> 2;
  const int tid  = threadIdx.x;
  const int g    = tid >> 6;
  const int lane = tid & 63;
  const int l15  = lane & 15;
  const int kg   = lane >> 4;

  cg::grid_group grid = cg::this_grid();

  __hip_atomic_store(&flags[bid * 256 + tid], 0u,
                     __ATOMIC_RELAXED, __HIP_MEMORY_SCOPE_AGENT);

  u32x4 bh[32];
  {
    const unsigned short* wr = Whh + ((size_t)(g * 1024 + ug * 16 + l15)) * 1024 + kg * 8;
#pragma unroll
    for (int kc = 0; kc < 32; ++kc) bh[kc] = *(const u32x4*)(wr + kc * 32);
  }
#pragma unroll
  for (int kc = 0; kc < 32; ++kc)
    asm volatile("" : "+v"(bh[kc]));
  {
    int r = tid >> 2, seg = tid & 3;
    int gg = r >> 4, uu = r & 15;
    const unsigned short* wsrc = Wxh + ((size_t)(gg * 1024 + ug * 16 + uu)) * 512;
    char* row = smem + L_WX + r * 1024;
    int sw = (r & 7) << 4;
#pragma unroll
    for (int j = 0; j < 16; ++j) {
      int chunk = seg * 16 + j;
      u32x4 v = *(const u32x4*)(wsrc + chunk * 8);
      *(u32x4*)(row + ((chunk * 16) ^ sw)) = v;
    }
  }
  const float bv = bias[g * 1024 + ug * 16 + l15];
  __syncthreads();

  grid.sync();

  const int eb = tid >> 4;
  const int eu = tid & 15;
  float c_reg = 0.0f;

  float* accl = (float*)(smem + L_ACC_S);
  unsigned short* houtl = (unsigned short*)(smem + L_HOUT_S);

  for (int t = 0; t < NT; ++t) {
    const int buf = t & 1, pbuf = buf ^ 1;

    f32x4 acc = {bv, bv, bv, bv};
    GUARD_PRE(acc);

    {
      const unsigned short* xp = xh + ((size_t)t * NB + bt * 16 + l15) * NI + kg * 8;
      const char* wxrow = smem + L_WX + (g * 16 + l15) * 1024;
      const int sw = (l15 & 7) << 4;
#pragma unroll
      for (int kc = 0; kc < 16; ++kc) {
        u32x4 a = *(const u32x4*)(xp + kc * 32);
        u32x4 b = *(const u32x4*)(wxrow + ((kc * 64 + kg * 16) ^ sw));
        asm("v_mfma_f32_16x16x32_f16 %0, %1, %2, %0" : "+v"(acc) : "v"(a), "v"(b));
      }
    }

    if (t > 0) {
      if (g == 0) {
        const unsigned int* cp = flags + ((t - 1) * 4 + bt) * 64 + lane;
        unsigned int fv;
        while (true) {
          asm volatile("global_load_dword %0, %1, off sc0 sc1\n\ts_waitcnt vmcnt(0)"
                       : "=v"(fv) : "v"(cp) : "memory");
          if (__all(fv == 1u)) break;
          __builtin_amdgcn_s_sleep(2);
        }
      }
      __syncthreads();

      const int sb = tid >> 4, sc = tid & 15;
      const unsigned short* hp = hglob + ((size_t)(pbuf * 4 + bt) * 16 + sb) * 1024 + sc * 8;
      u32x4 v0, v1, v2, v3, v4, v5, v6, v7;
      asm volatile(
          "global_load_dwordx4 %0, %[p], off sc0 sc1\n\t"
          "global_load_dwordx4 %1, %[p], off offset:256 sc0 sc1\n\t"
          "global_load_dwordx4 %2, %[p], off offset:512 sc0 sc1\n\t"
          "global_load_dwordx4 %3, %[p], off offset:768 sc0 sc1\n\t"
          "global_load_dwordx4 %4, %[p], off offset:1024 sc0 sc1\n\t"
          "global_load_dwordx4 %5, %[p], off offset:1280 sc0 sc1\n\t"
          "global_load_dwordx4 %6, %[p], off offset:1536 sc0 sc1\n\t"
          "global_load_dwordx4 %7, %[p], off offset:1792 sc0 sc1\n\t"
          "s_waitcnt vmcnt(0)"
          : "=&v"(v0), "=&v"(v1), "=&v"(v2), "=&v"(v3),
            "=&v"(v4), "=&v"(v5), "=&v"(v6), "=&v"(v7)
          : [p] "v"(hp)
          : "memory");
      char* hrow = smem + L_H + sb * 2048;
      const int sw = (sb & 7) << 4;
      *(u32x4*)(hrow + ((sc * 16 +    0) ^ sw)) = v0;
      *(u32x4*)(hrow + ((sc * 16 +  256) ^ sw)) = v1;
      *(u32x4*)(hrow + ((sc * 16 +  512) ^ sw)) = v2;
      *(u32x4*)(hrow + ((sc * 16 +  768) ^ sw)) = v3;
      *(u32x4*)(hrow + ((sc * 16 + 1024) ^ sw)) = v4;
      *(u32x4*)(hrow + ((sc * 16 + 1280) ^ sw)) = v5;
      *(u32x4*)(hrow + ((sc * 16 + 1536) ^ sw)) = v6;
      *(u32x4*)(hrow + ((sc * 16 + 1792) ^ sw)) = v7;
      __syncthreads();

      const char* hbase = smem + L_H + l15 * 2048;
      const int swh = (l15 & 7) << 4;
#pragma unroll
      for (int kc = 0; kc < 32; ++kc) {
        u32x4 a = *(const u32x4*)(hbase + ((kc * 64 + kg * 16) ^ swh));
        asm("v_mfma_f32_16x16x32_f16 %0, %1, %2, %0" : "+v"(acc) : "v"(a), "v"(bh[kc]));
      }
    }
    GUARD_POST(acc);

#pragma unroll
    for (int r = 0; r < 4; ++r)
      accl[g * 272 + (kg * 4 + r) * 17 + l15] = acc[r];
    __syncthreads();

    {
      float gf = accl[0 * 272 + eb * 17 + eu];
      float gi = accl[1 * 272 + eb * 17 + eu];
      float gc = accl[2 * 272 + eb * 17 + eu];
      float go = accl[3 * 272 + eb * 17 + eu];
      float f  = sigmoid_f(gf);
      float i  = sigmoid_f(gi);
      float cb = tanh_f(gc);
      float o  = sigmoid_f(go);
      float cn = f * c_reg + i * cb;
      c_reg = cn;
      float hn = o * tanh_f(cn);
      out[(((size_t)(bt * 16 + eb)) * NT + t) * NH + ug * 16 + eu] = hn;
      houtl[eb * 16 + eu] = f2h(hn);
    }
    __syncthreads();

    if (t + 1 < NT) {
      if (tid < 32) {
        u32x4 hv = *(const u32x4*)(houtl + tid * 8);
        unsigned short* dst = hglob + ((size_t)(buf * 4 + bt) * 16 + (tid >> 1)) * 1024
                            + ug * 16 + (tid & 1) * 8;
        asm volatile("global_store_dwordx4 %[p], %[v], off sc0 sc1\n\t"
                     "s_waitcnt vmcnt(0)"
                     :: [p] "v"(dst), [v] "v"(hv) : "memory");
      }
      if (tid == 0) {
        unsigned int* fp = flags + (t * 4 + bt) * 64 + ug;
        unsigned int one = 1u;
        asm volatile("global_store_dword %0, %1, off sc0 sc1"
                     :: "v"(fp), "v"(one) : "memory");
      }
    }
  }
}

// ---------------- persistent LSTM kernel: FAST path (two-chain MFMA) -------

__global__ __launch_bounds__(256, 1) void lstm_persist_fast(
    const unsigned short* __restrict__ Whh,
    const unsigned short* __restrict__ xg,
    const float* __restrict__ bias,
    unsigned short* __restrict__ hglob,
    unsigned int* __restrict__ flags,
    float* __restrict__ out) {
  extern __shared__ char smem[];
  const int bid  = blockIdx.x;
  const int bt   = bid & 3;
  const int ug   = bid >> 2;
  const int tid  = threadIdx.x;
  const int g    = tid >> 6;
  const int lane = tid & 63;
  const int l15  = lane & 15;
  const int kg   = lane >> 4;

  cg::grid_group grid = cg::this_grid();

  __hip_atomic_store(&flags[bid * 256 + tid], 0u,
                     __ATOMIC_RELAXED, __HIP_MEMORY_SCOPE_AGENT);

  u32x4 bh[32];
  {
    const unsigned short* wr = Whh + ((size_t)(g * 1024 + ug * 16 + l15)) * 1024 + kg * 8;
#pragma unroll
    for (int kc = 0; kc < 32; ++kc) bh[kc] = *(const u32x4*)(wr + kc * 32);
  }
#pragma unroll
  for (int kc = 0; kc < 32; ++kc)
    asm volatile("" : "+v"(bh[kc]));
  const float bv = bias[g * 1024 + ug * 16 + l15];
  __syncthreads();

  grid.sync();   // flag zeros visible; xg written (stream order before launch)

  const int eb = tid >> 4;
  const int eu = tid & 15;
  float c_reg = 0.0f;

  float* accl = (float*)(smem + L_ACC_F);
  unsigned short* houtl = (unsigned short*)(smem + L_HOUT_F);

  const size_t xg_eb = ((size_t)(bt * 16 + eb) * 4) * 1024 + ug * 16 + eu;
  const size_t xg_tstr = (size_t)NB * 4 * 1024;

  for (int t = 0; t < NT; ++t) {
    const int buf = t & 1, pbuf = buf ^ 1;

    const unsigned short* qp = xg + (size_t)t * xg_tstr + xg_eb;
    unsigned short q0 = qp[0];
    unsigned short q1 = qp[1024];
    unsigned short q2 = qp[2048];
    unsigned short q3 = qp[3072];

    // ---- two acc chains, BOTH dataflow-guarded (R15 idiom) ----
    f32x4 accA = {bv, bv, bv, bv};
    f32x4 accB = {0.0f, 0.0f, 0.0f, 0.0f};
    GUARD_PRE(accA);
    GUARD_PRE(accB);

    if (t > 0) {
      if (g == 0) {
        const unsigned int* cp = flags + ((t - 1) * 4 + bt) * 64 + lane;
        unsigned int fv;
        while (true) {
          asm volatile("global_load_dword %0, %1, off sc0 sc1\n\ts_waitcnt vmcnt(0)"
                       : "=v"(fv) : "v"(cp) : "memory");
          if (__all(fv == 1u)) break;
          __builtin_amdgcn_s_sleep(2);
        }
      }
      __syncthreads();

      const int sb = tid >> 4, sc = tid & 15;
      const unsigned short* hp = hglob + ((size_t)(pbuf * 4 + bt) * 16 + sb) * 1024 + sc * 8;
      u32x4 v0, v1, v2, v3, v4, v5, v6, v7;
      asm volatile(
          "global_load_dwordx4 %0, %[p], off sc0 sc1\n\t"
          "global_load_dwordx4 %1, %[p], off offset:256 sc0 sc1\n\t"
          "global_load_dwordx4 %2, %[p], off offset:512 sc0 sc1\n\t"
          "global_load_dwordx4 %3, %[p], off offset:768 sc0 sc1\n\t"
          "global_load_dwordx4 %4, %[p], off offset:1024 sc0 sc1\n\t"
          "global_load_dwordx4 %5, %[p], off offset:1280 sc0 sc1\n\t"
          "global_load_dwordx4 %6, %[p], off offset:1536 sc0 sc1\n\t"
          "global_load_dwordx4 %7, %[p], off offset:1792 sc0 sc1\n\t"
          "s_waitcnt vmcnt(0)"
          : "=&v"(v0), "=&v"(v1), "=&v"(v2), "=&v"(v3),
            "=&v"(v4), "=&v"(v5), "=&v"(v6), "=&v"(v7)
          : [p] "v"(hp)
          : "memory");
      char* hrow = smem + L_H + sb * 2048;
      const int sw = (sb & 7) << 4;
      *(u32x4*)(hrow + ((sc * 16 +    0) ^ sw)) = v0;
      *(u32x4*)(hrow + ((sc * 16 +  256) ^ sw)) = v1;
      *(u32x4*)(hrow + ((sc * 16 +  512) ^ sw)) = v2;
      *(u32x4*)(hrow + ((sc * 16 +  768) ^ sw)) = v3;
      *(u32x4*)(hrow + ((sc * 16 + 1024) ^ sw)) = v4;
      *(u32x4*)(hrow + ((sc * 16 + 1280) ^ sw)) = v5;
      *(u32x4*)(hrow + ((sc * 16 + 1536) ^ sw)) = v6;
      *(u32x4*)(hrow + ((sc * 16 + 1792) ^ sw)) = v7;
      __syncthreads();

      const char* hbase = smem + L_H + l15 * 2048;
      const int swh = (l15 & 7) << 4;
#pragma unroll
      for (int kc = 0; kc < 32; kc += 2) {
        u32x4 a0 = *(const u32x4*)(hbase + (((kc    ) * 64 + kg * 16) ^ swh));
        u32x4 a1 = *(const u32x4*)(hbase + (((kc + 1) * 64 + kg * 16) ^ swh));
        asm("v_mfma_f32_16x16x32_f16 %0, %1, %2, %0" : "+v"(accA) : "v"(a0), "v"(bh[kc]));
        asm("v_mfma_f32_16x16x32_f16 %0, %1, %2, %0" : "+v"(accB) : "v"(a1), "v"(bh[kc + 1]));
      }
    }
    GUARD_POST(accA);
    GUARD_POST(accB);

#pragma unroll
    for (int r = 0; r < 4; ++r)
      accl[g * 272 + (kg * 4 + r) * 17 + l15] = accA[r] + accB[r];
    __syncthreads();

    // ---- pointwise epilogue: add xg (pure VALU region) ----
    {
      float gf = accl[0 * 272 + eb * 17 + eu] + h2f(q0);
      float gi = accl[1 * 272 + eb * 17 + eu] + h2f(q1);
      float gc = accl[2 * 272 + eb * 17 + eu] + h2f(q2);
      float go = accl[3 * 272 + eb * 17 + eu] + h2f(q3);
      float f  = sigmoid_f(gf);
      float i  = sigmoid_f(gi);
      float cb = tanh_f(gc);
      float o  = sigmoid_f(go);
      float cn = f * c_reg + i * cb;
      c_reg = cn;
      float hn = o * tanh_f(cn);
      out[(((size_t)(bt * 16 + eb)) * NT + t) * NH + ug * 16 + eu] = hn;
      houtl[eb * 16 + eu] = f2h(hn);
    }
    __syncthreads();

    if (t + 1 < NT) {
      if (tid < 32) {
        u32x4 hv = *(const u32x4*)(houtl + tid * 8);
        unsigned short* dst = hglob + ((size_t)(buf * 4 + bt) * 16 + (tid >> 1)) * 1024
                            + ug * 16 + (tid & 1) * 8;
        asm volatile("global_store_dwordx4 %[p], %[v], off sc0 sc1\n\t"
                     "s_waitcnt vmcnt(0)"
                     :: [p] "v"(dst), [v] "v"(hv) : "memory");
      }
      if (tid == 0) {
        unsigned int* fp = flags + (t * 4 + bt) * 64 + ug;
        unsigned int one = 1u;
        asm volatile("global_store_dword %0, %1, off sc0 sc1"
                     :: "v"(fp), "v"(one) : "memory");
      }
    }
  }
}

// ---------------- host launcher ----------------

extern "C" void kernel_launch(void* const* d_in, const int* in_sizes, int n_in,
                              void* d_out, int out_size, void* d_ws, size_t ws_size,
                              hipStream_t stream) {
  (void)in_sizes; (void)n_in; (void)out_size;
  const float* x   = (const float*)d_in[0];
  const float* W_x = (const float*)d_in[1];
  const float* b_x = (const float*)d_in[2];
  const float* W_h = (const float*)d_in[3];
  const float* b_h = (const float*)d_in[4];
  const float* w_B = (const float*)d_in[5];
  const float* b_B = (const float*)d_in[6];
  float* out = (float*)d_out;

  char* ws = (char*)d_ws;
  unsigned short* Whh  = (unsigned short*)(ws + OFF_WHH);
  unsigned short* Wxh  = (unsigned short*)(ws + OFF_WXH);
  unsigned short* xhp  = (unsigned short*)(ws + OFF_XH);
  float*          bias = (float*)(ws + OFF_BIAS);
  unsigned short* hg   = (unsigned short*)(ws + OFF_HG);
  unsigned int*   flg  = (unsigned int*)(ws + OFF_FLG);
  unsigned short* xg   = (unsigned short*)(ws + OFF_XG);

  const size_t need_fast = (size_t)OFF_XG + (size_t)SZ_XG;
  const bool fast = (ws_size >= need_fast);

  hipFuncSetAttribute(reinterpret_cast<const void*>(lstm_persist_slow),
                      hipFuncAttributeMaxDynamicSharedMemorySize, LDS_SLOW);
  hipFuncSetAttribute(reinterpret_cast<const void*>(lstm_persist_fast),
                      hipFuncAttributeMaxDynamicSharedMemorySize, LDS_FAST);
  hipFuncSetAttribute(reinterpret_cast<const void*>(xg_gemm),
                      hipFuncAttributeMaxDynamicSharedMemorySize, XG_LDS);

  pack_w_kernel<<<dim3(6144), dim3(256), 0, stream>>>(W_h, W_x, Whh, Wxh);
  pack_x_kernel<<<dim3(4096), dim3(256), 0, stream>>>(x, xhp);
  prep_small_kernel<<<dim3(16), dim3(256), 0, stream>>>(b_x, b_h, w_B, b_B, bias);

  if (fast) {
    xg_gemm<<<dim3(2048), dim3(256), XG_LDS, stream>>>(Wxh, xhp, xg);
    void* kargs[] = {(void*)&Whh, (void*)&xg, (void*)&bias,
                     (void*)&hg, (void*)&flg, (void*)&out};
    hipLaunchCooperativeKernel(reinterpret_cast<void*>(lstm_persist_fast),
                               dim3(256), dim3(256), kargs, LDS_FAST, stream);
  } else {
    void* kargs[] = {(void*)&Whh, (void*)&Wxh, (void*)&xhp, (void*)&bias,
                     (void*)&hg, (void*)&flg, (void*)&out};
    hipLaunchCooperativeKernel(reinterpret_cast<void*>(lstm_persist_slow),
                               dim3(256), dim3(256), kargs, LDS_SLOW, stream);
  }
}

// Round 21
// 1081.493 us; speedup vs baseline: 1.0948x; 1.0948x over previous
//
#include <hip/hip_runtime.h>
#include <hip/hip_cooperative_groups.h>

namespace cg = cooperative_groups;

// LSTM B=64 T=256 I=512 H=1024, fp32 in/out, fp16 MFMA compute (fp32 accum).
// Round 21: exact R19 (validated 1096us: single-chain persist, xg_gemm v4)
// + ONE delta: defer the out[] HBM store until AFTER the h-publish + flag,
// so the publish vmcnt(0) drains only the 16B h store (not the out store).

using f32x4 = __attribute__((ext_vector_type(4))) float;
using u32x4 = __attribute__((ext_vector_type(4))) unsigned int;

#define NB 64
#define NT 256
#define NI 512
#define NH 1024

// ---- workspace layout (bytes) ----
#define OFF_WHH  0u
#define SZ_WHH   (4u*1024u*1024u*2u)        // fp16 [4 g][1024 u][1024 k]
#define OFF_WXH  (OFF_WHH + SZ_WHH)
#define SZ_WXH   (4u*1024u*512u*2u)         // fp16 [4 g][1024 u][512 k]
#define OFF_XH   (OFF_WXH + SZ_WXH)
#define SZ_XH    (256u*64u*512u*2u)         // fp16 [T][B][I]
#define OFF_BIAS (OFF_XH + SZ_XH)
#define SZ_BIAS  (4096u*4u)
#define OFF_HG   (OFF_BIAS + SZ_BIAS)
#define SZ_HG    (2u*4u*16u*1024u*2u)       // fp16 [2 buf][4 bt][16 b][1024 u]
#define OFF_FLG  (OFF_HG + SZ_HG)
#define SZ_FLG   (256u*4u*64u*4u)           // u32 [T][4 bt][64 ug] per-producer
#define OFF_XG   (OFF_FLG + SZ_FLG)
#define SZ_XG    (256ull*64ull*4ull*1024ull*2ull)  // fp16 [T][B][4 g][1024 u]

// ---- LDS layouts (bytes) ----
#define L_H    0        // 16 rows x 2048 B (fp16 [16 b][1024 k], XOR-swizzled)
#define L_WX   32768    // (slow path) 64 rows x 1024 B swizzled W_x
#define L_ACC_S  98304  // slow path: fp32 [4 g][16 b][17]
#define L_HOUT_S 102656
#define LDS_SLOW 103168
#define L_ACC_F  32768  // fast path: fp32 [4 g][272] = 4352 B
#define L_HOUT_F 37120  // fp16 [16 b][16 u] = 512 B
#define LDS_FAST 37632  // R15-validated
#define XG_LDS   65536  // v4: 64 rows x 1024 B swizzled W_x

// dataflow-carried hazard guards (validated R15)
#define GUARD_PRE(acc)  asm volatile("s_nop 1\ns_nop 1" : "+v"(acc))
#define GUARD_POST(acc) asm volatile("s_nop 7\ns_nop 7\ns_nop 7" : "+v"(acc))

__device__ __forceinline__ unsigned short f2h(float f) {
  _Float16 h = (_Float16)f;
  return __builtin_bit_cast(unsigned short, h);
}
__device__ __forceinline__ float h2f(unsigned short u) {
  _Float16 h = __builtin_bit_cast(_Float16, u);
  return (float)h;
}
__device__ __forceinline__ float sigmoid_f(float x) {
  return 1.0f / (1.0f + __expf(-x));
}
__device__ __forceinline__ float tanh_f(float x) {
  float xc = fminf(fmaxf(x, -15.0f), 15.0f);
  float e = __expf(2.0f * xc);
  return 1.0f - 2.0f / (e + 1.0f);
}

// ---------------- prep kernels ----------------

__global__ __launch_bounds__(256) void pack_w_kernel(
    const float* __restrict__ Wh, const float* __restrict__ Wx,
    unsigned short* __restrict__ WhP, unsigned short* __restrict__ WxP) {
  int base = (blockIdx.x * 256 + threadIdx.x) * 4;
  const int nWh = 4 * 1024 * 1024;
  const int nWx = 4 * 1024 * 512;
  if (base < nWh) {
    const float* s = Wh + base;
    unsigned int o0 = (unsigned int)f2h(s[0]) | ((unsigned int)f2h(s[1]) << 16);
    unsigned int o1 = (unsigned int)f2h(s[2]) | ((unsigned int)f2h(s[3]) << 16);
    ((unsigned int*)(WhP + base))[0] = o0;
    ((unsigned int*)(WhP + base))[1] = o1;
  } else {
    int b2 = base - nWh;
    if (b2 < nWx) {
      const float* s = Wx + b2;
      unsigned int o0 = (unsigned int)f2h(s[0]) | ((unsigned int)f2h(s[1]) << 16);
      unsigned int o1 = (unsigned int)f2h(s[2]) | ((unsigned int)f2h(s[3]) << 16);
      ((unsigned int*)(WxP + b2))[0] = o0;
      ((unsigned int*)(WxP + b2))[1] = o1;
    }
  }
}

// transpose x[B][T][I] fp32 -> xh[T][B][I] fp16
__global__ __launch_bounds__(256) void pack_x_kernel(
    const float* __restrict__ x, unsigned short* __restrict__ xh) {
  int gid = blockIdx.x * 256 + threadIdx.x;     // over B*T*(I/8) = 1,048,576
  int i8 = gid & 63;
  int t  = (gid >> 6) & 255;
  int b  = gid >> 14;
  const float* s = x + (((size_t)b * NT + t) * NI + i8 * 8);
  unsigned int w[4];
#pragma unroll
  for (int j = 0; j < 4; ++j)
    w[j] = (unsigned int)f2h(s[2*j]) | ((unsigned int)f2h(s[2*j+1]) << 16);
  u32x4 v = {w[0], w[1], w[2], w[3]};
  *(u32x4*)(xh + (((size_t)t * NB + b) * NI + i8 * 8)) = v;
}

__global__ __launch_bounds__(256) void prep_small_kernel(
    const float* __restrict__ b_x, const float* __restrict__ b_h,
    const float* __restrict__ w_B, const float* __restrict__ b_B,
    float* __restrict__ bias) {
  int gid = blockIdx.x * 256 + threadIdx.x;
  if (gid < 4096) bias[gid] = b_x[gid] + b_h[gid] + w_B[gid] + b_B[gid];
}

// ---------------- xg precompute GEMM v4 (A-reuse across gates; R19) --------
// xg[t][b][g][u] = sum_k xh[t][b][k] * Wx[g*1024+u][k]   (fp16 out)
// Grid 4096 = (mchunk 64) x (ug 64). Block stages W_x[ug] (64KB LDS).
// Wave w owns M-tiles mc*16 + w*4 + i: loads A once, 4 gates sequentially.

__global__ __launch_bounds__(256) void xg_gemm(
    const unsigned short* __restrict__ Wxh,
    const unsigned short* __restrict__ xh,
    unsigned short* __restrict__ xg) {
  extern __shared__ char smem[];
  const int ug = blockIdx.x & 63;
  const int mc = blockIdx.x >> 6;       // 0..63
  const int tid  = threadIdx.x;
  const int w    = tid >> 6;
  const int l15  = tid & 15;
  const int kg   = (tid & 63) >> 4;

  {
    int r = tid >> 2, seg = tid & 3;           // r = g'*16+u' (0..63)
    int gg = r >> 4, uu = r & 15;
    const unsigned short* wsrc = Wxh + ((size_t)(gg * 1024 + ug * 16 + uu)) * 512;
    char* row = smem + r * 1024;
    int sw = (r & 7) << 4;
#pragma unroll
    for (int j = 0; j < 16; ++j) {
      int chunk = seg * 16 + j;
      u32x4 v = *(const u32x4*)(wsrc + chunk * 8);
      *(u32x4*)(row + ((chunk * 16) ^ sw)) = v;
    }
  }
  __syncthreads();

  const int swl = (l15 & 7) << 4;

#pragma unroll 1
  for (int i = 0; i < 4; ++i) {
    const int mt = mc * 16 + w * 4 + i;
    const int t  = mt >> 2;
    const int b0 = (mt & 3) << 4;

    u32x4 xa[16];
    const unsigned short* xp = xh + ((size_t)t * NB + b0 + l15) * NI + kg * 8;
#pragma unroll
    for (int kc = 0; kc < 16; ++kc) xa[kc] = *(const u32x4*)(xp + kc * 32);

#pragma unroll 1
    for (int gg = 0; gg < 4; ++gg) {
      f32x4 acc = {0.0f, 0.0f, 0.0f, 0.0f};
      GUARD_PRE(acc);
      const char* wxrow = smem + (gg * 16 + l15) * 1024;
#pragma unroll
      for (int kc = 0; kc < 16; ++kc) {
        u32x4 b = *(const u32x4*)(wxrow + ((kc * 64 + kg * 16) ^ swl));
        asm("v_mfma_f32_16x16x32_f16 %0, %1, %2, %0" : "+v"(acc) : "v"(xa[kc]), "v"(b));
      }
      GUARD_POST(acc);

#pragma unroll
      for (int r = 0; r < 4; ++r) {
        size_t addr = (((size_t)t * NB + b0 + kg * 4 + r) * 4 + gg) * 1024 + ug * 16 + l15;
        xg[addr] = f2h(acc[r]);
      }
    }
  }
}

// ---------------- persistent LSTM kernel: SLOW path (R15-validated) --------

__global__ __launch_bounds__(256, 1) void lstm_persist_slow(
    const unsigned short* __restrict__ Whh,
    const unsigned short* __restrict__ Wxh,
    const unsigned short* __restrict__ xh,
    const float* __restrict__ bias,
    unsigned short* __restrict__ hglob,
    unsigned int* __restrict__ flags,
    float* __restrict__ out) {
  extern __shared__ char smem[];
  const int bid  = blockIdx.x;
  const int bt   = bid & 3;
  const int ug   = bid >> 2;
  const int tid  = threadIdx.x;
  const int g    = tid >> 6;
  const int lane = tid & 63;
  const int l15  = lane & 15;
  const int kg   = lane >> 4;

  cg::grid_group grid = cg::this_grid();

  __hip_atomic_store(&flags[bid * 256 + tid], 0u,
                     __ATOMIC_RELAXED, __HIP_MEMORY_SCOPE_AGENT);

  u32x4 bh[32];
  {
    const unsigned short* wr = Whh + ((size_t)(g * 1024 + ug * 16 + l15)) * 1024 + kg * 8;
#pragma unroll
    for (int kc = 0; kc < 32; ++kc) bh[kc] = *(const u32x4*)(wr + kc * 32);
  }
#pragma unroll
  for (int kc = 0; kc < 32; ++kc)
    asm volatile("" : "+v"(bh[kc]));
  {
    int r = tid >> 2, seg = tid & 3;
    int gg = r >> 4, uu = r & 15;
    const unsigned short* wsrc = Wxh + ((size_t)(gg * 1024 + ug * 16 + uu)) * 512;
    char* row = smem + L_WX + r * 1024;
    int sw = (r & 7) << 4;
#pragma unroll
    for (int j = 0; j < 16; ++j) {
      int chunk = seg * 16 + j;
      u32x4 v = *(const u32x4*)(wsrc + chunk * 8);
      *(u32x4*)(row + ((chunk * 16) ^ sw)) = v;
    }
  }
  const float bv = bias[g * 1024 + ug * 16 + l15];
  __syncthreads();

  grid.sync();

  const int eb = tid >> 4;
  const int eu = tid & 15;
  float c_reg = 0.0f;

  float* accl = (float*)(smem + L_ACC_S);
  unsigned short* houtl = (unsigned short*)(smem + L_HOUT_S);

  for (int t = 0; t < NT; ++t) {
    const int buf = t & 1, pbuf = buf ^ 1;

    f32x4 acc = {bv, bv, bv, bv};
    GUARD_PRE(acc);

    {
      const unsigned short* xp = xh + ((size_t)t * NB + bt * 16 + l15) * NI + kg * 8;
      const char* wxrow = smem + L_WX + (g * 16 + l15) * 1024;
      const int sw = (l15 & 7) << 4;
#pragma unroll
      for (int kc = 0; kc < 16; ++kc) {
        u32x4 a = *(const u32x4*)(xp + kc * 32);
        u32x4 b = *(const u32x4*)(wxrow + ((kc * 64 + kg * 16) ^ sw));
        asm("v_mfma_f32_16x16x32_f16 %0, %1, %2, %0" : "+v"(acc) : "v"(a), "v"(b));
      }
    }

    if (t > 0) {
      if (g == 0) {
        const unsigned int* cp = flags + ((t - 1) * 4 + bt) * 64 + lane;
        unsigned int fv;
        while (true) {
          asm volatile("global_load_dword %0, %1, off sc0 sc1\n\ts_waitcnt vmcnt(0)"
                       : "=v"(fv) : "v"(cp) : "memory");
          if (__all(fv == 1u)) break;
          __builtin_amdgcn_s_sleep(2);
        }
      }
      __syncthreads();

      const int sb = tid >> 4, sc = tid & 15;
      const unsigned short* hp = hglob + ((size_t)(pbuf * 4 + bt) * 16 + sb) * 1024 + sc * 8;
      u32x4 v0, v1, v2, v3, v4, v5, v6, v7;
      asm volatile(
          "global_load_dwordx4 %0, %[p], off sc0 sc1\n\t"
          "global_load_dwordx4 %1, %[p], off offset:256 sc0 sc1\n\t"
          "global_load_dwordx4 %2, %[p], off offset:512 sc0 sc1\n\t"
          "global_load_dwordx4 %3, %[p], off offset:768 sc0 sc1\n\t"
          "global_load_dwordx4 %4, %[p], off offset:1024 sc0 sc1\n\t"
          "global_load_dwordx4 %5, %[p], off offset:1280 sc0 sc1\n\t"
          "global_load_dwordx4 %6, %[p], off offset:1536 sc0 sc1\n\t"
          "global_load_dwordx4 %7, %[p], off offset:1792 sc0 sc1\n\t"
          "s_waitcnt vmcnt(0)"
          : "=&v"(v0), "=&v"(v1), "=&v"(v2), "=&v"(v3),
            "=&v"(v4), "=&v"(v5), "=&v"(v6), "=&v"(v7)
          : [p] "v"(hp)
          : "memory");
      char* hrow = smem + L_H + sb * 2048;
      const int sw = (sb & 7) << 4;
      *(u32x4*)(hrow + ((sc * 16 +    0) ^ sw)) = v0;
      *(u32x4*)(hrow + ((sc * 16 +  256) ^ sw)) = v1;
      *(u32x4*)(hrow + ((sc * 16 +  512) ^ sw)) = v2;
      *(u32x4*)(hrow + ((sc * 16 +  768) ^ sw)) = v3;
      *(u32x4*)(hrow + ((sc * 16 + 1024) ^ sw)) = v4;
      *(u32x4*)(hrow + ((sc * 16 + 1280) ^ sw)) = v5;
      *(u32x4*)(hrow + ((sc * 16 + 1536) ^ sw)) = v6;
      *(u32x4*)(hrow + ((sc * 16 + 1792) ^ sw)) = v7;
      __syncthreads();

      const char* hbase = smem + L_H + l15 * 2048;
      const int swh = (l15 & 7) << 4;
#pragma unroll
      for (int kc = 0; kc < 32; ++kc) {
        u32x4 a = *(const u32x4*)(hbase + ((kc * 64 + kg * 16) ^ swh));
        asm("v_mfma_f32_16x16x32_f16 %0, %1, %2, %0" : "+v"(acc) : "v"(a), "v"(bh[kc]));
      }
    }
    GUARD_POST(acc);

#pragma unroll
    for (int r = 0; r < 4; ++r)
      accl[g * 272 + (kg * 4 + r) * 17 + l15] = acc[r];
    __syncthreads();

    {
      float gf = accl[0 * 272 + eb * 17 + eu];
      float gi = accl[1 * 272 + eb * 17 + eu];
      float gc = accl[2 * 272 + eb * 17 + eu];
      float go = accl[3 * 272 + eb * 17 + eu];
      float f  = sigmoid_f(gf);
      float i  = sigmoid_f(gi);
      float cb = tanh_f(gc);
      float o  = sigmoid_f(go);
      float cn = f * c_reg + i * cb;
      c_reg = cn;
      float hn = o * tanh_f(cn);
      out[(((size_t)(bt * 16 + eb)) * NT + t) * NH + ug * 16 + eu] = hn;
      houtl[eb * 16 + eu] = f2h(hn);
    }
    __syncthreads();

    if (t + 1 < NT) {
      if (tid < 32) {
        u32x4 hv = *(const u32x4*)(houtl + tid * 8);
        unsigned short* dst = hglob + ((size_t)(buf * 4 + bt) * 16 + (tid >> 1)) * 1024
                            + ug * 16 + (tid & 1) * 8;
        asm volatile("global_store_dwordx4 %[p], %[v], off sc0 sc1\n\t"
                     "s_waitcnt vmcnt(0)"
                     :: [p] "v"(dst), [v] "v"(hv) : "memory");
      }
      if (tid == 0) {
        unsigned int* fp = flags + (t * 4 + bt) * 64 + ug;
        unsigned int one = 1u;
        asm volatile("global_store_dword %0, %1, off sc0 sc1"
                     :: "v"(fp), "v"(one) : "memory");
      }
    }
  }
}

// ---------------- persistent LSTM kernel: FAST path (R19 + deferred out) ---

__global__ __launch_bounds__(256, 1) void lstm_persist_fast(
    const unsigned short* __restrict__ Whh,
    const unsigned short* __restrict__ xg,
    const float* __restrict__ bias,
    unsigned short* __restrict__ hglob,
    unsigned int* __restrict__ flags,
    float* __restrict__ out) {
  extern __shared__ char smem[];
  const int bid  = blockIdx.x;
  const int bt   = bid & 3;
  const int ug   = bid >> 2;
  const int tid  = threadIdx.x;
  const int g    = tid >> 6;
  const int lane = tid & 63;
  const int l15  = lane & 15;
  const int kg   = lane >> 4;

  cg::grid_group grid = cg::this_grid();

  __hip_atomic_store(&flags[bid * 256 + tid], 0u,
                     __ATOMIC_RELAXED, __HIP_MEMORY_SCOPE_AGENT);

  u32x4 bh[32];
  {
    const unsigned short* wr = Whh + ((size_t)(g * 1024 + ug * 16 + l15)) * 1024 + kg * 8;
#pragma unroll
    for (int kc = 0; kc < 32; ++kc) bh[kc] = *(const u32x4*)(wr + kc * 32);
  }
#pragma unroll
  for (int kc = 0; kc < 32; ++kc)
    asm volatile("" : "+v"(bh[kc]));
  const float bv = bias[g * 1024 + ug * 16 + l15];
  __syncthreads();

  grid.sync();   // flag zeros visible; xg written (stream order before launch)

  const int eb = tid >> 4;
  const int eu = tid & 15;
  float c_reg = 0.0f;

  float* accl = (float*)(smem + L_ACC_F);
  unsigned short* houtl = (unsigned short*)(smem + L_HOUT_F);

  const size_t xg_eb = ((size_t)(bt * 16 + eb) * 4) * 1024 + ug * 16 + eu;
  const size_t xg_tstr = (size_t)NB * 4 * 1024;
  float* const outp = out + (((size_t)(bt * 16 + eb)) * NT) * NH + ug * 16 + eu;

  for (int t = 0; t < NT; ++t) {
    const int buf = t & 1, pbuf = buf ^ 1;

    const unsigned short* qp = xg + (size_t)t * xg_tstr + xg_eb;
    unsigned short q0 = qp[0];
    unsigned short q1 = qp[1024];
    unsigned short q2 = qp[2048];
    unsigned short q3 = qp[3072];

    f32x4 acc = {bv, bv, bv, bv};
    GUARD_PRE(acc);

    if (t > 0) {
      if (g == 0) {
        const unsigned int* cp = flags + ((t - 1) * 4 + bt) * 64 + lane;
        unsigned int fv;
        while (true) {
          asm volatile("global_load_dword %0, %1, off sc0 sc1\n\ts_waitcnt vmcnt(0)"
                       : "=v"(fv) : "v"(cp) : "memory");
          if (__all(fv == 1u)) break;
          __builtin_amdgcn_s_sleep(2);
        }
      }
      __syncthreads();

      const int sb = tid >> 4, sc = tid & 15;
      const unsigned short* hp = hglob + ((size_t)(pbuf * 4 + bt) * 16 + sb) * 1024 + sc * 8;
      u32x4 v0, v1, v2, v3, v4, v5, v6, v7;
      asm volatile(
          "global_load_dwordx4 %0, %[p], off sc0 sc1\n\t"
          "global_load_dwordx4 %1, %[p], off offset:256 sc0 sc1\n\t"
          "global_load_dwordx4 %2, %[p], off offset:512 sc0 sc1\n\t"
          "global_load_dwordx4 %3, %[p], off offset:768 sc0 sc1\n\t"
          "global_load_dwordx4 %4, %[p], off offset:1024 sc0 sc1\n\t"
          "global_load_dwordx4 %5, %[p], off offset:1280 sc0 sc1\n\t"
          "global_load_dwordx4 %6, %[p], off offset:1536 sc0 sc1\n\t"
          "global_load_dwordx4 %7, %[p], off offset:1792 sc0 sc1\n\t"
          "s_waitcnt vmcnt(0)"
          : "=&v"(v0), "=&v"(v1), "=&v"(v2), "=&v"(v3),
            "=&v"(v4), "=&v"(v5), "=&v"(v6), "=&v"(v7)
          : [p] "v"(hp)
          : "memory");
      char* hrow = smem + L_H + sb * 2048;
      const int sw = (sb & 7) << 4;
      *(u32x4*)(hrow + ((sc * 16 +    0) ^ sw)) = v0;
      *(u32x4*)(hrow + ((sc * 16 +  256) ^ sw)) = v1;
      *(u32x4*)(hrow + ((sc * 16 +  512) ^ sw)) = v2;
      *(u32x4*)(hrow + ((sc * 16 +  768) ^ sw)) = v3;
      *(u32x4*)(hrow + ((sc * 16 + 1024) ^ sw)) = v4;
      *(u32x4*)(hrow + ((sc * 16 + 1280) ^ sw)) = v5;
      *(u32x4*)(hrow + ((sc * 16 + 1536) ^ sw)) = v6;
      *(u32x4*)(hrow + ((sc * 16 + 1792) ^ sw)) = v7;
      __syncthreads();

      const char* hbase = smem + L_H + l15 * 2048;
      const int swh = (l15 & 7) << 4;
#pragma unroll
      for (int kc = 0; kc < 32; ++kc) {
        u32x4 a = *(const u32x4*)(hbase + ((kc * 64 + kg * 16) ^ swh));
        asm("v_mfma_f32_16x16x32_f16 %0, %1, %2, %0" : "+v"(acc) : "v"(a), "v"(bh[kc]));
      }
    }
    GUARD_POST(acc);

#pragma unroll
    for (int r = 0; r < 4; ++r)
      accl[g * 272 + (kg * 4 + r) * 17 + l15] = acc[r];
    __syncthreads();

    // ---- pointwise epilogue: add xg; DEFER the out store ----
    float hn;
    {
      float gf = accl[0 * 272 + eb * 17 + eu] + h2f(q0);
      float gi = accl[1 * 272 + eb * 17 + eu] + h2f(q1);
      float gc = accl[2 * 272 + eb * 17 + eu] + h2f(q2);
      float go = accl[3 * 272 + eb * 17 + eu] + h2f(q3);
      float f  = sigmoid_f(gf);
      float i  = sigmoid_f(gi);
      float cb = tanh_f(gc);
      float o  = sigmoid_f(go);
      float cn = f * c_reg + i * cb;
      c_reg = cn;
      hn = o * tanh_f(cn);
      houtl[eb * 16 + eu] = f2h(hn);
    }
    __syncthreads();

    // ---- publish h(t) (drain covers ONLY the h store) + flag ----
    if (t + 1 < NT) {
      if (tid < 32) {
        u32x4 hv = *(const u32x4*)(houtl + tid * 8);
        unsigned short* dst = hglob + ((size_t)(buf * 4 + bt) * 16 + (tid >> 1)) * 1024
                            + ug * 16 + (tid & 1) * 8;
        asm volatile("global_store_dwordx4 %[p], %[v], off sc0 sc1\n\t"
                     "s_waitcnt vmcnt(0)"
                     :: [p] "v"(dst), [v] "v"(hv) : "memory");
      }
      if (tid == 0) {
        unsigned int* fp = flags + (t * 4 + bt) * 64 + ug;
        unsigned int one = 1u;
        asm volatile("global_store_dword %0, %1, off sc0 sc1"
                     :: "v"(fp), "v"(one) : "memory");
      }
    }

    // ---- deferred out store (fire-and-forget; completes under next poll) ----
    outp[(size_t)t * NH] = hn;
  }
}

// ---------------- host launcher ----------------

extern "C" void kernel_launch(void* const* d_in, const int* in_sizes, int n_in,
                              void* d_out, int out_size, void* d_ws, size_t ws_size,
                              hipStream_t stream) {
  (void)in_sizes; (void)n_in; (void)out_size;
  const float* x   = (const float*)d_in[0];
  const float* W_x = (const float*)d_in[1];
  const float* b_x = (const float*)d_in[2];
  const float* W_h = (const float*)d_in[3];
  const float* b_h = (const float*)d_in[4];
  const float* w_B = (const float*)d_in[5];
  const float* b_B = (const float*)d_in[6];
  float* out = (float*)d_out;

  char* ws = (char*)d_ws;
  unsigned short* Whh  = (unsigned short*)(ws + OFF_WHH);
  unsigned short* Wxh  = (unsigned short*)(ws + OFF_WXH);
  unsigned short* xhp  = (unsigned short*)(ws + OFF_XH);
  float*          bias = (float*)(ws + OFF_BIAS);
  unsigned short* hg   = (unsigned short*)(ws + OFF_HG);
  unsigned int*   flg  = (unsigned int*)(ws + OFF_FLG);
  unsigned short* xg   = (unsigned short*)(ws + OFF_XG);

  const size_t need_fast = (size_t)OFF_XG + (size_t)SZ_XG;
  const bool fast = (ws_size >= need_fast);

  hipFuncSetAttribute(reinterpret_cast<const void*>(lstm_persist_slow),
                      hipFuncAttributeMaxDynamicSharedMemorySize, LDS_SLOW);
  hipFuncSetAttribute(reinterpret_cast<const void*>(lstm_persist_fast),
                      hipFuncAttributeMaxDynamicSharedMemorySize, LDS_FAST);
  hipFuncSetAttribute(reinterpret_cast<const void*>(xg_gemm),
                      hipFuncAttributeMaxDynamicSharedMemorySize, XG_LDS);

  pack_w_kernel<<<dim3(6144), dim3(256), 0, stream>>>(W_h, W_x, Whh, Wxh);
  pack_x_kernel<<<dim3(4096), dim3(256), 0, stream>>>(x, xhp);
  prep_small_kernel<<<dim3(16), dim3(256), 0, stream>>>(b_x, b_h, w_B, b_B, bias);

  if (fast) {
    xg_gemm<<<dim3(4096), dim3(256), XG_LDS, stream>>>(Wxh, xhp, xg);
    void* kargs[] = {(void*)&Whh, (void*)&xg, (void*)&bias,
                     (void*)&hg, (void*)&flg, (void*)&out};
    hipLaunchCooperativeKernel(reinterpret_cast<void*>(lstm_persist_fast),
                               dim3(256), dim3(256), kargs, LDS_FAST, stream);
  } else {
    void* kargs[] = {(void*)&Whh, (void*)&Wxh, (void*)&xhp, (void*)&bias,
                     (void*)&hg, (void*)&flg, (void*)&out};
    hipLaunchCooperativeKernel(reinterpret_cast<void*>(lstm_persist_slow),
                               dim3(256), dim3(256), kargs, LDS_SLOW, stream);
  }
}